// Round 14
// baseline (6865.281 us; speedup 1.0000x reference)
//
#include <hip/hip_runtime.h>
#include <math.h>

#define SEQ   2048
#define BATCH 64
#define NIN   256
#define NHID  512
#define NOUT  128

#define NSL 8      // j-slices (64 j each)
#define JSL 64

// wire: [par][b][slice][128 words]; value -> word pair (tag<<16|hi16,
// tag<<16|lo16). Self-validating words, system scope (sc0 sc1) only.
// (r4 lesson: sc0-only polls spin on stale L1 forever.)
#define WIRE_WORDS (2*BATCH*NSL*128)               // 131072 (512 KB)
#define WIRE_BYTES ((size_t)WIRE_WORDS*4)
#define HFIN_BYTES ((size_t)BATCH*NHID*4)          // 128 KB
#define XP_BYTES   ((size_t)SEQ*BATCH*NHID*4)      // 268.4 MB x-projection

typedef unsigned int u32;
typedef u32 u32x2 __attribute__((ext_vector_type(2)));

__device__ __forceinline__ u32x2 ld8_ic(const u32* p) {
  u32x2 r;
  asm volatile("global_load_dwordx2 %0, %1, off sc0 sc1"
               : "=v"(r) : "v"(p) : "memory");
  return r;
}
__device__ __forceinline__ void st8_ic(u32* p, u32x2 v) {
  asm volatile("global_store_dwordx2 %0, %1, off sc0 sc1"
               :: "v"(p), "v"(v) : "memory");
}
__device__ __forceinline__ void wait_vm0() {
  asm volatile("s_waitcnt vmcnt(0)" ::: "memory");
  __builtin_amdgcn_sched_barrier(0);   // uses stay after the wait (rule #18)
}

// tanh(x) = 1 - 2/(exp2(2*log2e*x)+1): 5 VALU ops, exact +-1 saturation.
__device__ __forceinline__ float fast_tanh(float x) {
  const float e = __builtin_amdgcn_exp2f(x * 2.8853900817779268f);
  const float r = __builtin_amdgcn_rcpf(e + 1.0f);
  return fmaf(-2.0f, r, 1.0f);
}

// ---------------- x-projection GEMM (verified r11-r13) ----------------------
__global__ __launch_bounds__(512, 1)
void xproj_kernel(const float* __restrict__ x,
                  const float* __restrict__ Wih,
                  const float* __restrict__ bih,
                  const float* __restrict__ bhh,
                  float* __restrict__ xp)
{
  const int bj = blockIdx.x & 7;
  const int bm = blockIdx.x >> 3;
  const int tid = threadIdx.x;
  const int tx = tid & 15, ty = tid >> 4;

  __shared__ __align__(16) float  wT[NIN][68];
  __shared__ __align__(16) float4 xS[64][66];

  for (int it = 0; it < 32; ++it) {
    const int widx = tid + (it << 9);
    const int k = widx >> 6, j = widx & 63;
    wT[k][j] = Wih[(size_t)(bj*64 + j)*NIN + k];
  }
  const int jg = bj*64 + tx*4;
  float4 bv;
  bv.x = bih[jg+0]+bhh[jg+0]; bv.y = bih[jg+1]+bhh[jg+1];
  bv.z = bih[jg+2]+bhh[jg+2]; bv.w = bih[jg+3]+bhh[jg+3];
  __syncthreads();

  for (int mt = 0; mt < 8; ++mt) {
    const size_t r0 = (size_t)bm*512 + mt*64;
    for (int it = 0; it < 8; ++it) {
      const int f = tid + (it << 9);
      const int m = f >> 6, kq = f & 63;
      xS[m][kq] = *(const float4*)&x[(r0 + m)*NIN + (kq << 2)];
    }
    __syncthreads();

    float acc[2][4];
    #pragma unroll
    for (int q = 0; q < 2; ++q)
      #pragma unroll
      for (int jj = 0; jj < 4; ++jj) acc[q][jj] = 0.f;

    for (int kq = 0; kq < 64; ++kq) {
      const float4 xv0 = xS[ty*2+0][kq];
      const float4 xv1 = xS[ty*2+1][kq];
      #pragma unroll
      for (int i = 0; i < 4; ++i) {
        const float4 wv = *(const float4*)&wT[(kq<<2)+i][tx*4];
        const float xi0 = (i==0)?xv0.x:(i==1)?xv0.y:(i==2)?xv0.z:xv0.w;
        const float xi1 = (i==0)?xv1.x:(i==1)?xv1.y:(i==2)?xv1.z:xv1.w;
        acc[0][0]=fmaf(xi0,wv.x,acc[0][0]); acc[0][1]=fmaf(xi0,wv.y,acc[0][1]);
        acc[0][2]=fmaf(xi0,wv.z,acc[0][2]); acc[0][3]=fmaf(xi0,wv.w,acc[0][3]);
        acc[1][0]=fmaf(xi1,wv.x,acc[1][0]); acc[1][1]=fmaf(xi1,wv.y,acc[1][1]);
        acc[1][2]=fmaf(xi1,wv.z,acc[1][2]); acc[1][3]=fmaf(xi1,wv.w,acc[1][3]);
      }
    }
    float4 o0, o1;
    o0.x = acc[0][0]+bv.x; o0.y = acc[0][1]+bv.y;
    o0.z = acc[0][2]+bv.z; o0.w = acc[0][3]+bv.w;
    o1.x = acc[1][0]+bv.x; o1.y = acc[1][1]+bv.y;
    o1.z = acc[1][2]+bv.z; o1.w = acc[1][3]+bv.w;
    *(float4*)&xp[(r0 + ty*2 + 0)*NHID + jg] = o0;
    *(float4*)&xp[(r0 + ty*2 + 1)*NHID + jg] = o1;
    __syncthreads();
  }
}

// ---------------- 256-block recurrent kernel: batch-paired, W streamed ------
// block (bp,sj): 2 batch rows x 64 j. 512 thr = 16 jg(4j) x 32 kl(16k).
// W loaded once per 2-step iteration (short live range; laundered pointer
// defeats LICM hoist->spill). Stream: 2 MB/XCD/step. One barrier per step.
__global__ __launch_bounds__(512, 2)
void rnn_seq8_kernel(const float* __restrict__ xp,
                     const float* __restrict__ Whh,
                     u32* __restrict__ wire,
                     float* __restrict__ hfin)
{
  const int bid = blockIdx.x;
  const int bp  = bid >> 3;          // batch pair 0..31
  const int sj  = bid & 7;           // j-slice 0..7 (== XCD under round-robin)
  const int tid = threadIdx.x;
  const int jg  = tid >> 5;          // 0..15 j-group (4 j)
  const int kl  = tid & 31;          // 0..31 k-chunk (16 k)
  const int w   = tid >> 6, lane = tid & 63;

  // hS[par][row][k>>4][k&15], stride 36 (r13: negligible conflicts)
  __shared__ __align__(16) float hS[2][2][32][36];   // 36.9 KB
  for (int i = tid; i < 2*2*32*36; i += 512) (&hS[0][0][0][0])[i] = 0.f;

  // lane's owned output after the width-32 butterfly
  const int jloc  = jg*4 + ((kl >> 1) & 3);    // 0..63 within slice
  const int rr    = kl & 1;                    // batch row within pair
  const int bown  = bp*2 + rr;
  const int jglob = sj*JSL + jloc;

  const float* xptr = xp + (size_t)bown*NHID + jglob;
  float xpC = *xptr;
  xptr += BATCH*NHID;                          // -> t=1

  const float* wb = Whh + (size_t)(sj*JSL + jg*4)*NHID + kl*16;

  // publish (kl<8): wire + own-slice LDS slot
  u32* wo0 = wire + ((((size_t)0*BATCH + bown)*NSL + sj) << 7) + (jloc << 1);
  u32* wo1 = wire + ((((size_t)1*BATCH + bown)*NSL + sj) << 7) + (jloc << 1);
  const int okc = sj*4 + (jloc >> 4), okk = jloc & 15;
  float* pL0 = &hS[0][rr][okc][okk];
  float* pL1 = &hS[1][rr][okc][okk];

  // stage roles: wave w<7 stages foreign slice sp, BOTH rows (2 polls)
  const int sp = (sj + 1 + w) & 7;
  const u32* wfa0 = wire + ((((size_t)0*BATCH + bp*2+0)*NSL + sp) << 7) + (lane << 1);
  const u32* wfa1 = wire + ((((size_t)0*BATCH + bp*2+1)*NSL + sp) << 7) + (lane << 1);
  const u32* wfb0 = wire + ((((size_t)1*BATCH + bp*2+0)*NSL + sp) << 7) + (lane << 1);
  const u32* wfb1 = wire + ((((size_t)1*BATCH + bp*2+1)*NSL + sp) << 7) + (lane << 1);
  const int skc = sp*4 + (lane >> 4), skk = lane & 15;
  float* sda0 = &hS[0][0][skc][skk];
  float* sda1 = &hS[0][1][skc][skk];
  float* sdb0 = &hS[1][0][skc][skk];
  float* sdb1 = &hS[1][1][skc][skk];

  const float* dA0 = &hS[0][0][kl][0];   // + DROW for row 1
  const float* dA1 = &hS[1][0][kl][0];
  const int DROW = 32*36;

  __syncthreads();
  float hlast = 0.f;

#define RSTEP(T, DA, PL, WO, WF0, WF1, SD0, SD1)                              \
  {                                                                           \
    const bool last_ = (T) == SEQ - 1;                                        \
    float xpN = 0.f;                                                          \
    if (!last_) { xpN = *xptr; xptr += BATCH*NHID; }                          \
    float A0=0.f,A1=0.f,A2=0.f,A3=0.f,A4=0.f,A5=0.f,A6=0.f,A7=0.f;            \
    _Pragma("unroll")                                                         \
    for (int i = 0; i < 4; ++i) {                                             \
      const float4 h0 = *(const float4*)((DA) + 4*i);                         \
      const float4 h1 = *(const float4*)((DA) + DROW + 4*i);                  \
      A0=fmaf(w0[i].x,h0.x,A0); A0=fmaf(w0[i].y,h0.y,A0);                     \
      A0=fmaf(w0[i].z,h0.z,A0); A0=fmaf(w0[i].w,h0.w,A0);                     \
      A1=fmaf(w0[i].x,h1.x,A1); A1=fmaf(w0[i].y,h1.y,A1);                     \
      A1=fmaf(w0[i].z,h1.z,A1); A1=fmaf(w0[i].w,h1.w,A1);                     \
      A2=fmaf(w1[i].x,h0.x,A2); A2=fmaf(w1[i].y,h0.y,A2);                     \
      A2=fmaf(w1[i].z,h0.z,A2); A2=fmaf(w1[i].w,h0.w,A2);                     \
      A3=fmaf(w1[i].x,h1.x,A3); A3=fmaf(w1[i].y,h1.y,A3);                     \
      A3=fmaf(w1[i].z,h1.z,A3); A3=fmaf(w1[i].w,h1.w,A3);                     \
      A4=fmaf(w2[i].x,h0.x,A4); A4=fmaf(w2[i].y,h0.y,A4);                     \
      A4=fmaf(w2[i].z,h0.z,A4); A4=fmaf(w2[i].w,h0.w,A4);                     \
      A5=fmaf(w2[i].x,h1.x,A5); A5=fmaf(w2[i].y,h1.y,A5);                     \
      A5=fmaf(w2[i].z,h1.z,A5); A5=fmaf(w2[i].w,h1.w,A5);                     \
      A6=fmaf(w3[i].x,h0.x,A6); A6=fmaf(w3[i].y,h0.y,A6);                     \
      A6=fmaf(w3[i].z,h0.z,A6); A6=fmaf(w3[i].w,h0.w,A6);                     \
      A7=fmaf(w3[i].x,h1.x,A7); A7=fmaf(w3[i].y,h1.y,A7);                     \
      A7=fmaf(w3[i].z,h1.z,A7); A7=fmaf(w3[i].w,h1.w,A7);                     \
    }                                                                         \
    /* width-32 butterfly over kl; lane ends with (jj=(kl>>1)&3, rr=kl&1) */  \
    float s_;                                                                 \
    {                                                                         \
      const float t0_=__shfl_xor(A0,1,32), t1_=__shfl_xor(A1,1,32);           \
      const float t2_=__shfl_xor(A2,1,32), t3_=__shfl_xor(A3,1,32);           \
      const float t4_=__shfl_xor(A4,1,32), t5_=__shfl_xor(A5,1,32);           \
      const float t6_=__shfl_xor(A6,1,32), t7_=__shfl_xor(A7,1,32);           \
      float B0_,B1_,B2_,B3_;                                                  \
      if (kl & 1) { B0_=A1+t1_; B1_=A3+t3_; B2_=A5+t5_; B3_=A7+t7_; }         \
      else        { B0_=A0+t0_; B1_=A2+t2_; B2_=A4+t4_; B3_=A6+t6_; }         \
      const float u0_=__shfl_xor(B0_,2,32), u1_=__shfl_xor(B1_,2,32);         \
      const float u2_=__shfl_xor(B2_,2,32), u3_=__shfl_xor(B3_,2,32);         \
      float C0_,C1_;                                                          \
      if (kl & 2) { C0_=B1_+u1_; C1_=B3_+u3_; }                               \
      else        { C0_=B0_+u0_; C1_=B2_+u2_; }                               \
      const float v0_=__shfl_xor(C0_,4,32), v1_=__shfl_xor(C1_,4,32);         \
      s_ = (kl & 4) ? (C1_+v1_) : (C0_+v0_);                                  \
      s_ += __shfl_xor(s_, 8, 32);                                            \
      s_ += __shfl_xor(s_, 16, 32);                                           \
    }                                                                         \
    const float hn_ = fast_tanh(s_ + xpC);                                    \
    if (!last_) {                                                             \
      const u32 tg_ = (u32)(T) + 1u;                                          \
      if (kl < 8) {                                                           \
        *(PL) = hn_;                                                          \
        const u32 bits_ = __float_as_uint(hn_);                               \
        u32x2 pv_;                                                            \
        pv_.x = (tg_<<16) | (bits_>>16);                                      \
        pv_.y = (tg_<<16) | (bits_ & 0xffffu);                                \
        st8_ic((WO), pv_);                                                    \
      }                                                                       \
      if (w < 7) {                                                            \
        u32x2 va_ = ld8_ic(WF0), vb_ = ld8_ic(WF1);                           \
        wait_vm0();                                                           \
        u32 pend_ = 3u; int g_ = 1 << 17;                                     \
        for (;;) {                                                            \
          const bool ok0_ = __all((va_.x>>16)==tg_ && (va_.y>>16)==tg_);      \
          const bool ok1_ = __all((vb_.x>>16)==tg_ && (vb_.y>>16)==tg_);      \
          if ((pend_&1u) && ok0_) {                                           \
            *(SD0) = __uint_as_float((va_.x<<16)|(va_.y&0xffffu));            \
            pend_ &= ~1u;                                                     \
          }                                                                   \
          if ((pend_&2u) && ok1_) {                                           \
            *(SD1) = __uint_as_float((vb_.x<<16)|(vb_.y&0xffffu));            \
            pend_ &= ~2u;                                                     \
          }                                                                   \
          if (!pend_ || --g_ == 0) break;  /* bug => absmax fail, not hang */ \
          if (pend_&1u) va_ = ld8_ic(WF0);                                    \
          if (pend_&2u) vb_ = ld8_ic(WF1);                                    \
          wait_vm0();                                                         \
        }                                                                     \
      }                                                                       \
      __syncthreads();               /* hS[next par] complete */              \
      xpC = xpN;                                                              \
    }                                                                         \
    hlast = hn_;                                                              \
  }

  for (int t = 0; t < SEQ; t += 2) {
    // W tile for BOTH steps of this iteration (4j x 16k = 64 floats).
    // Laundered pointer: prevents LICM hoist (whose spill caused r11-r13's
    // per-step scratch/L2 reloads at double the necessary volume).
    const float* wp = wb;
    asm volatile("" : "+v"(wp));
    float4 w0[4], w1[4], w2[4], w3[4];
    #pragma unroll
    for (int i = 0; i < 4; ++i) {
      w0[i] = *(const float4*)(wp + 0*NHID + 4*i);
      w1[i] = *(const float4*)(wp + 1*NHID + 4*i);
      w2[i] = *(const float4*)(wp + 2*NHID + 4*i);
      w3[i] = *(const float4*)(wp + 3*NHID + 4*i);
    }
    RSTEP(t,     dA0, pL1, wo1, wfb0, wfb1, sdb0, sdb1); // read par0 -> par1
    RSTEP(t + 1, dA1, pL0, wo0, wfa0, wfa1, sda0, sda1); // read par1 -> par0
  }
#undef RSTEP

  if (kl < 8) hfin[(size_t)bown*NHID + jglob] = hlast;   // h(2048)
}

// ---------------- fallback (r8, known-pass): batch-split, W row-major -------
__global__ __launch_bounds__(512, 2)
void rnn_seq_fb_kernel(const float* __restrict__ xp,
                       const float* __restrict__ Whh,
                       float* __restrict__ hfin)
{
  const int b = blockIdx.x;
  const int j = threadIdx.x;
  __shared__ __align__(16) float hh[2][NHID];
  hh[0][j] = 0.f;
  const float* wrow = Whh + (size_t)j*NHID;
  const float* xcol = xp + (size_t)b*NHID + j;
  float xpC = xcol[0];
  float hnew = 0.f;
  __syncthreads();
  for (int t = 0; t < SEQ; ++t) {
    const int par = t & 1;
    float xpN = 0.f;
    if (t + 1 < SEQ) xpN = xcol[(size_t)(t+1)*(BATCH*NHID)];
    const float* hA = hh[par];
    float a0=0.f,a1=0.f,a2=0.f,a3=0.f;
    #pragma unroll 8
    for (int kq = 0; kq < 128; ++kq) {
      const float4 wv = *(const float4*)&wrow[kq << 2];
      const float4 hv = *(const float4*)&hA[kq << 2];
      a0 = fmaf(wv.x, hv.x, a0);
      a1 = fmaf(wv.y, hv.y, a1);
      a2 = fmaf(wv.z, hv.z, a2);
      a3 = fmaf(wv.w, hv.w, a3);
    }
    hnew = tanhf((a0+a1)+(a2+a3) + xpC);
    hh[par ^ 1][j] = hnew;
    xpC = xpN;
    __syncthreads();
  }
  hfin[(size_t)b*NHID + j] = hnew;
}

// ---------------- output projection ----------------
__global__ __launch_bounds__(NOUT, 1)
void rnn_out_kernel(const float* __restrict__ hfin,
                    const float* __restrict__ Who,
                    const float* __restrict__ bho,
                    float* __restrict__ out)
{
  const int b = blockIdx.x;
  const int o = threadIdx.x;
  __shared__ __align__(16) float hB[NHID];
  for (int k = o; k < NHID; k += NOUT) hB[k] = hfin[(size_t)b*NHID + k];
  __syncthreads();
  const float* wr = Who + (size_t)o*NHID;
  float a0=0.f,a1=0.f,a2=0.f,a3=0.f;
  for (int k = 0; k < NHID; k += 4) {
    const float4 wv = *(const float4*)&wr[k];
    a0 = fmaf(wv.x, hB[k  ], a0);
    a1 = fmaf(wv.y, hB[k+1], a1);
    a2 = fmaf(wv.z, hB[k+2], a2);
    a3 = fmaf(wv.w, hB[k+3], a3);
  }
  out[(size_t)b*NOUT + o] = (a0+a1)+(a2+a3) + bho[o];
}

extern "C" void kernel_launch(void* const* d_in, const int* in_sizes, int n_in,
                              void* d_out, int out_size, void* d_ws, size_t ws_size,
                              hipStream_t stream)
{
  const float* x   = (const float*)d_in[0];
  const float* Wih = (const float*)d_in[1];
  const float* bih = (const float*)d_in[2];
  const float* Whh = (const float*)d_in[3];
  const float* bhh = (const float*)d_in[4];
  const float* Who = (const float*)d_in[5];
  const float* bho = (const float*)d_in[6];
  float* out = (float*)d_out;

  const size_t need = WIRE_BYTES + HFIN_BYTES + XP_BYTES;

  if (ws_size >= need) {
    u32*   wire = (u32*)d_ws;
    float* hfin = (float*)((char*)d_ws + WIRE_BYTES);
    float* xp   = (float*)((char*)d_ws + WIRE_BYTES + HFIN_BYTES);

    hipMemsetAsync(wire, 0, WIRE_BYTES, stream);   // tags 0; step0 wants tag 1
    xproj_kernel <<<dim3(2048), dim3(512), 0, stream>>>(x, Wih, bih, bhh, xp);
    rnn_seq8_kernel<<<dim3(256), dim3(512), 0, stream>>>(xp, Whh, wire, hfin);
    rnn_out_kernel<<<dim3(BATCH), dim3(NOUT), 0, stream>>>(hfin, Who, bho, out);
  } else {
    float* hfin = (float*)d_ws;
    float* xp   = (float*)((char*)d_ws + HFIN_BYTES);
    xproj_kernel<<<dim3(2048), dim3(512), 0, stream>>>(x, Wih, bih, bhh, xp);
    rnn_seq_fb_kernel<<<dim3(BATCH), dim3(512), 0, stream>>>(xp, Whh, hfin);
    rnn_out_kernel<<<dim3(BATCH), dim3(NOUT), 0, stream>>>(hfin, Who, bho, out);
  }
}

// Round 15
// 4758.517 us; speedup vs baseline: 1.4427x; 1.4427x over previous
//
#include <hip/hip_runtime.h>
#include <math.h>

#define SEQ   2048
#define BATCH 64
#define NIN   256
#define NHID  512
#define NOUT  128

#define NSL 8      // j-slices (64 j each)
#define JSL 64

// wire: [par][b][slice][128 words]; value -> word pair (tag<<16|hi16,
// tag<<16|lo16). Self-validating words, system scope (sc0 sc1) only.
// (r4 lesson: sc0-only polls spin on stale L1 forever.)
#define WIRE_WORDS (2*BATCH*NSL*128)               // 131072 (512 KB)
#define WIRE_BYTES ((size_t)WIRE_WORDS*4)
#define HFIN_BYTES ((size_t)BATCH*NHID*4)          // 128 KB
#define XP_BYTES   ((size_t)SEQ*BATCH*NHID*4)      // 268.4 MB x-projection

typedef unsigned int u32;
typedef u32 u32x2 __attribute__((ext_vector_type(2)));

__device__ __forceinline__ u32x2 ld8_ic(const u32* p) {
  u32x2 r;
  asm volatile("global_load_dwordx2 %0, %1, off sc0 sc1"
               : "=v"(r) : "v"(p) : "memory");
  return r;
}
__device__ __forceinline__ void st8_ic(u32* p, u32x2 v) {
  asm volatile("global_store_dwordx2 %0, %1, off sc0 sc1"
               :: "v"(p), "v"(v) : "memory");
}
__device__ __forceinline__ void wait_vm0() {
  asm volatile("s_waitcnt vmcnt(0)" ::: "memory");
  __builtin_amdgcn_sched_barrier(0);   // uses stay after the wait (rule #18)
}

// tanh(x) = 1 - 2/(exp2(2*log2e*x)+1): 5 VALU ops, exact +-1 saturation.
__device__ __forceinline__ float fast_tanh(float x) {
  const float e = __builtin_amdgcn_exp2f(x * 2.8853900817779268f);
  const float r = __builtin_amdgcn_rcpf(e + 1.0f);
  return fmaf(-2.0f, r, 1.0f);
}

// ---------------- x-projection GEMM (verified r11-r14) ----------------------
__global__ __launch_bounds__(512, 1)
void xproj_kernel(const float* __restrict__ x,
                  const float* __restrict__ Wih,
                  const float* __restrict__ bih,
                  const float* __restrict__ bhh,
                  float* __restrict__ xp)
{
  const int bj = blockIdx.x & 7;
  const int bm = blockIdx.x >> 3;
  const int tid = threadIdx.x;
  const int tx = tid & 15, ty = tid >> 4;

  __shared__ __align__(16) float  wT[NIN][68];
  __shared__ __align__(16) float4 xS[64][66];

  for (int it = 0; it < 32; ++it) {
    const int widx = tid + (it << 9);
    const int k = widx >> 6, j = widx & 63;
    wT[k][j] = Wih[(size_t)(bj*64 + j)*NIN + k];
  }
  const int jg = bj*64 + tx*4;
  float4 bv;
  bv.x = bih[jg+0]+bhh[jg+0]; bv.y = bih[jg+1]+bhh[jg+1];
  bv.z = bih[jg+2]+bhh[jg+2]; bv.w = bih[jg+3]+bhh[jg+3];
  __syncthreads();

  for (int mt = 0; mt < 8; ++mt) {
    const size_t r0 = (size_t)bm*512 + mt*64;
    for (int it = 0; it < 8; ++it) {
      const int f = tid + (it << 9);
      const int m = f >> 6, kq = f & 63;
      xS[m][kq] = *(const float4*)&x[(r0 + m)*NIN + (kq << 2)];
    }
    __syncthreads();

    float acc[2][4];
    #pragma unroll
    for (int q = 0; q < 2; ++q)
      #pragma unroll
      for (int jj = 0; jj < 4; ++jj) acc[q][jj] = 0.f;

    for (int kq = 0; kq < 64; ++kq) {
      const float4 xv0 = xS[ty*2+0][kq];
      const float4 xv1 = xS[ty*2+1][kq];
      #pragma unroll
      for (int i = 0; i < 4; ++i) {
        const float4 wv = *(const float4*)&wT[(kq<<2)+i][tx*4];
        const float xi0 = (i==0)?xv0.x:(i==1)?xv0.y:(i==2)?xv0.z:xv0.w;
        const float xi1 = (i==0)?xv1.x:(i==1)?xv1.y:(i==2)?xv1.z:xv1.w;
        acc[0][0]=fmaf(xi0,wv.x,acc[0][0]); acc[0][1]=fmaf(xi0,wv.y,acc[0][1]);
        acc[0][2]=fmaf(xi0,wv.z,acc[0][2]); acc[0][3]=fmaf(xi0,wv.w,acc[0][3]);
        acc[1][0]=fmaf(xi1,wv.x,acc[1][0]); acc[1][1]=fmaf(xi1,wv.y,acc[1][1]);
        acc[1][2]=fmaf(xi1,wv.z,acc[1][2]); acc[1][3]=fmaf(xi1,wv.w,acc[1][3]);
      }
    }
    float4 o0, o1;
    o0.x = acc[0][0]+bv.x; o0.y = acc[0][1]+bv.y;
    o0.z = acc[0][2]+bv.z; o0.w = acc[0][3]+bv.w;
    o1.x = acc[1][0]+bv.x; o1.y = acc[1][1]+bv.y;
    o1.z = acc[1][2]+bv.z; o1.w = acc[1][3]+bv.w;
    *(float4*)&xp[(r0 + ty*2 + 0)*NHID + jg] = o0;
    *(float4*)&xp[(r0 + ty*2 + 1)*NHID + jg] = o1;
    __syncthreads();
  }
}

// ---------------- 256-block recurrent kernel: W_hh in LDS -------------------
// block (bp,sj): 2 batch rows x 64 j. 512 thr = 16 jg(4j) x 32 kl(16k).
// W slice (128 KB) lives in LDS, quad-major swizzled layout wq[i][row][kl]
// (float4 granules): every wave-wide b128 hits all 32 banks exactly 8x (the
// minimum). The in-loop __syncthreads clobbers LDS -> loads can't be LICM'd
// -> no giant W live range -> no spill (r11-r14 lesson).
__global__ __launch_bounds__(512, 1)
void rnn_seq8_kernel(const float* __restrict__ xp,
                     const float* __restrict__ Whh,
                     u32* __restrict__ wire,
                     float* __restrict__ hfin)
{
  const int bid = blockIdx.x;
  const int bp  = bid >> 3;          // batch pair 0..31
  const int sj  = bid & 7;           // j-slice 0..7
  const int tid = threadIdx.x;
  const int jg  = tid >> 5;          // 0..15 j-group (4 j)
  const int kl  = tid & 31;          // 0..31 k-chunk (16 k)
  const int w   = tid >> 6, lane = tid & 63;

  __shared__ __align__(16) float4 wq[NIN*32];        // 131072 B: [i][row][kl]
  __shared__ __align__(16) float  hS[2][2][32][36];  // 18432 B

  // ---- one-time W slice load -> swizzled LDS (coalesced global reads) ----
  for (int it = 0; it < 16; ++it) {
    const int linear = tid + (it << 9);    // 0..8191 float4s
    const int r = linear >> 7;             // row 0..63
    const int c = linear & 127;            // float4 col
    const int klq = c >> 2, iq = c & 3;
    wq[(((iq << 6) + r) << 5) + klq] =
        *(const float4*)&Whh[(size_t)(sj*JSL + r)*NHID + (c << 2)];
  }
  for (int i = tid; i < 2*2*32*36; i += 512) (&hS[0][0][0][0])[i] = 0.f;

  // lane's owned output after the width-32 butterfly
  const int jloc  = jg*4 + ((kl >> 1) & 3);
  const int rr    = kl & 1;
  const int bown  = bp*2 + rr;
  const int jglob = sj*JSL + jloc;

  const float* xptr = xp + (size_t)bown*NHID + jglob;
  float xpC = *xptr;
  xptr += BATCH*NHID;                          // -> t=1

  // publish (kl<8): wire + own-slice LDS slot
  u32* wo0 = wire + ((((size_t)0*BATCH + bown)*NSL + sj) << 7) + (jloc << 1);
  u32* wo1 = wire + ((((size_t)1*BATCH + bown)*NSL + sj) << 7) + (jloc << 1);
  const int okc = sj*4 + (jloc >> 4), okk = jloc & 15;
  float* pL0 = &hS[0][rr][okc][okk];
  float* pL1 = &hS[1][rr][okc][okk];

  // stage roles: wave w<7 stages foreign slice sp, BOTH rows
  const int sp = (sj + 1 + w) & 7;
  const u32* wfa0 = wire + ((((size_t)0*BATCH + bp*2+0)*NSL + sp) << 7) + (lane << 1);
  const u32* wfa1 = wire + ((((size_t)0*BATCH + bp*2+1)*NSL + sp) << 7) + (lane << 1);
  const u32* wfb0 = wire + ((((size_t)1*BATCH + bp*2+0)*NSL + sp) << 7) + (lane << 1);
  const u32* wfb1 = wire + ((((size_t)1*BATCH + bp*2+1)*NSL + sp) << 7) + (lane << 1);
  const int skc = sp*4 + (lane >> 4), skk = lane & 15;
  float* sda0 = &hS[0][0][skc][skk];
  float* sda1 = &hS[0][1][skc][skk];
  float* sdb0 = &hS[1][0][skc][skk];
  float* sdb1 = &hS[1][1][skc][skk];

  const float* dA0 = &hS[0][0][kl][0];   // + DROW for row 1
  const float* dA1 = &hS[1][0][kl][0];
  const int DROW = 32*36;
  const int jg4 = jg << 2;

  __syncthreads();
  float hlast = 0.f;

#define RSTEP(T, DA, PL, WO, WF0, WF1, SD0, SD1)                              \
  {                                                                           \
    const bool last_ = (T) == SEQ - 1;                                        \
    float xpN = 0.f;                                                          \
    if (!last_) { xpN = *xptr; xptr += BATCH*NHID; }                          \
    float A0=0.f,A1=0.f,A2=0.f,A3=0.f,A4=0.f,A5=0.f,A6=0.f,A7=0.f;            \
    _Pragma("unroll")                                                         \
    for (int i = 0; i < 4; ++i) {                                             \
      const float4 h0 = *(const float4*)((DA) + 4*i);                         \
      const float4 h1 = *(const float4*)((DA) + DROW + 4*i);                  \
      const float4 W0 = wq[(((i<<6) + jg4 + 0) << 5) + kl];                   \
      const float4 W1 = wq[(((i<<6) + jg4 + 1) << 5) + kl];                   \
      const float4 W2 = wq[(((i<<6) + jg4 + 2) << 5) + kl];                   \
      const float4 W3 = wq[(((i<<6) + jg4 + 3) << 5) + kl];                   \
      A0=fmaf(W0.x,h0.x,A0); A0=fmaf(W0.y,h0.y,A0);                           \
      A0=fmaf(W0.z,h0.z,A0); A0=fmaf(W0.w,h0.w,A0);                           \
      A1=fmaf(W0.x,h1.x,A1); A1=fmaf(W0.y,h1.y,A1);                           \
      A1=fmaf(W0.z,h1.z,A1); A1=fmaf(W0.w,h1.w,A1);                           \
      A2=fmaf(W1.x,h0.x,A2); A2=fmaf(W1.y,h0.y,A2);                           \
      A2=fmaf(W1.z,h0.z,A2); A2=fmaf(W1.w,h0.w,A2);                           \
      A3=fmaf(W1.x,h1.x,A3); A3=fmaf(W1.y,h1.y,A3);                           \
      A3=fmaf(W1.z,h1.z,A3); A3=fmaf(W1.w,h1.w,A3);                           \
      A4=fmaf(W2.x,h0.x,A4); A4=fmaf(W2.y,h0.y,A4);                           \
      A4=fmaf(W2.z,h0.z,A4); A4=fmaf(W2.w,h0.w,A4);                           \
      A5=fmaf(W2.x,h1.x,A5); A5=fmaf(W2.y,h1.y,A5);                           \
      A5=fmaf(W2.z,h1.z,A5); A5=fmaf(W2.w,h1.w,A5);                           \
      A6=fmaf(W3.x,h0.x,A6); A6=fmaf(W3.y,h0.y,A6);                           \
      A6=fmaf(W3.z,h0.z,A6); A6=fmaf(W3.w,h0.w,A6);                           \
      A7=fmaf(W3.x,h1.x,A7); A7=fmaf(W3.y,h1.y,A7);                           \
      A7=fmaf(W3.z,h1.z,A7); A7=fmaf(W3.w,h1.w,A7);                           \
    }                                                                         \
    /* width-32 butterfly over kl; lane ends with (jj=(kl>>1)&3, rr=kl&1) */  \
    float s_;                                                                 \
    {                                                                         \
      const float t0_=__shfl_xor(A0,1,32), t1_=__shfl_xor(A1,1,32);           \
      const float t2_=__shfl_xor(A2,1,32), t3_=__shfl_xor(A3,1,32);           \
      const float t4_=__shfl_xor(A4,1,32), t5_=__shfl_xor(A5,1,32);           \
      const float t6_=__shfl_xor(A6,1,32), t7_=__shfl_xor(A7,1,32);           \
      float B0_,B1_,B2_,B3_;                                                  \
      if (kl & 1) { B0_=A1+t1_; B1_=A3+t3_; B2_=A5+t5_; B3_=A7+t7_; }         \
      else        { B0_=A0+t0_; B1_=A2+t2_; B2_=A4+t4_; B3_=A6+t6_; }         \
      const float u0_=__shfl_xor(B0_,2,32), u1_=__shfl_xor(B1_,2,32);         \
      const float u2_=__shfl_xor(B2_,2,32), u3_=__shfl_xor(B3_,2,32);         \
      float C0_,C1_;                                                          \
      if (kl & 2) { C0_=B1_+u1_; C1_=B3_+u3_; }                               \
      else        { C0_=B0_+u0_; C1_=B2_+u2_; }                               \
      const float v0_=__shfl_xor(C0_,4,32), v1_=__shfl_xor(C1_,4,32);         \
      s_ = (kl & 4) ? (C1_+v1_) : (C0_+v0_);                                  \
      s_ += __shfl_xor(s_, 8, 32);                                            \
      s_ += __shfl_xor(s_, 16, 32);                                           \
    }                                                                         \
    const float hn_ = fast_tanh(s_ + xpC);                                    \
    if (!last_) {                                                             \
      const u32 tg_ = (u32)(T) + 1u;                                          \
      if (kl < 8) {                                                           \
        *(PL) = hn_;                                                          \
        const u32 bits_ = __float_as_uint(hn_);                               \
        u32x2 pv_;                                                            \
        pv_.x = (tg_<<16) | (bits_>>16);                                      \
        pv_.y = (tg_<<16) | (bits_ & 0xffffu);                                \
        st8_ic((WO), pv_);                                                    \
      }                                                                       \
      if (w < 7) {                                                            \
        u32x2 va_ = ld8_ic(WF0), vb_ = ld8_ic(WF1);                           \
        wait_vm0();                                                           \
        u32 pend_ = 3u; int g_ = 1 << 17;                                     \
        for (;;) {                                                            \
          const bool ok0_ = __all((va_.x>>16)==tg_ && (va_.y>>16)==tg_);      \
          const bool ok1_ = __all((vb_.x>>16)==tg_ && (vb_.y>>16)==tg_);      \
          if ((pend_&1u) && ok0_) {                                           \
            *(SD0) = __uint_as_float((va_.x<<16)|(va_.y&0xffffu));            \
            pend_ &= ~1u;                                                     \
          }                                                                   \
          if ((pend_&2u) && ok1_) {                                           \
            *(SD1) = __uint_as_float((vb_.x<<16)|(vb_.y&0xffffu));            \
            pend_ &= ~2u;                                                     \
          }                                                                   \
          if (!pend_ || --g_ == 0) break;  /* bug => absmax fail, not hang */ \
          if (pend_&1u) va_ = ld8_ic(WF0);                                    \
          if (pend_&2u) vb_ = ld8_ic(WF1);                                    \
          wait_vm0();                                                         \
        }                                                                     \
      }                                                                       \
      __syncthreads();               /* hS[next par] complete */              \
      xpC = xpN;                                                              \
    }                                                                         \
    hlast = hn_;                                                              \
  }

  for (int t = 0; t < SEQ; t += 2) {
    RSTEP(t,     dA0, pL1, wo1, wfb0, wfb1, sdb0, sdb1); // read par0 -> par1
    RSTEP(t + 1, dA1, pL0, wo0, wfa0, wfa1, sda0, sda1); // read par1 -> par0
  }
#undef RSTEP

  if (kl < 8) hfin[(size_t)bown*NHID + jglob] = hlast;   // h(2048)
}

// ---------------- fallback (r8, known-pass): batch-split, W row-major -------
__global__ __launch_bounds__(512, 2)
void rnn_seq_fb_kernel(const float* __restrict__ xp,
                       const float* __restrict__ Whh,
                       float* __restrict__ hfin)
{
  const int b = blockIdx.x;
  const int j = threadIdx.x;
  __shared__ __align__(16) float hh[2][NHID];
  hh[0][j] = 0.f;
  const float* wrow = Whh + (size_t)j*NHID;
  const float* xcol = xp + (size_t)b*NHID + j;
  float xpC = xcol[0];
  float hnew = 0.f;
  __syncthreads();
  for (int t = 0; t < SEQ; ++t) {
    const int par = t & 1;
    float xpN = 0.f;
    if (t + 1 < SEQ) xpN = xcol[(size_t)(t+1)*(BATCH*NHID)];
    const float* hA = hh[par];
    float a0=0.f,a1=0.f,a2=0.f,a3=0.f;
    #pragma unroll 8
    for (int kq = 0; kq < 128; ++kq) {
      const float4 wv = *(const float4*)&wrow[kq << 2];
      const float4 hv = *(const float4*)&hA[kq << 2];
      a0 = fmaf(wv.x, hv.x, a0);
      a1 = fmaf(wv.y, hv.y, a1);
      a2 = fmaf(wv.z, hv.z, a2);
      a3 = fmaf(wv.w, hv.w, a3);
    }
    hnew = tanhf((a0+a1)+(a2+a3) + xpC);
    hh[par ^ 1][j] = hnew;
    xpC = xpN;
    __syncthreads();
  }
  hfin[(size_t)b*NHID + j] = hnew;
}

// ---------------- output projection ----------------
__global__ __launch_bounds__(NOUT, 1)
void rnn_out_kernel(const float* __restrict__ hfin,
                    const float* __restrict__ Who,
                    const float* __restrict__ bho,
                    float* __restrict__ out)
{
  const int b = blockIdx.x;
  const int o = threadIdx.x;
  __shared__ __align__(16) float hB[NHID];
  for (int k = o; k < NHID; k += NOUT) hB[k] = hfin[(size_t)b*NHID + k];
  __syncthreads();
  const float* wr = Who + (size_t)o*NHID;
  float a0=0.f,a1=0.f,a2=0.f,a3=0.f;
  for (int k = 0; k < NHID; k += 4) {
    const float4 wv = *(const float4*)&wr[k];
    a0 = fmaf(wv.x, hB[k  ], a0);
    a1 = fmaf(wv.y, hB[k+1], a1);
    a2 = fmaf(wv.z, hB[k+2], a2);
    a3 = fmaf(wv.w, hB[k+3], a3);
  }
  out[(size_t)b*NOUT + o] = (a0+a1)+(a2+a3) + bho[o];
}

extern "C" void kernel_launch(void* const* d_in, const int* in_sizes, int n_in,
                              void* d_out, int out_size, void* d_ws, size_t ws_size,
                              hipStream_t stream)
{
  const float* x   = (const float*)d_in[0];
  const float* Wih = (const float*)d_in[1];
  const float* bih = (const float*)d_in[2];
  const float* Whh = (const float*)d_in[3];
  const float* bhh = (const float*)d_in[4];
  const float* Who = (const float*)d_in[5];
  const float* bho = (const float*)d_in[6];
  float* out = (float*)d_out;

  const size_t need = WIRE_BYTES + HFIN_BYTES + XP_BYTES;

  if (ws_size >= need) {
    u32*   wire = (u32*)d_ws;
    float* hfin = (float*)((char*)d_ws + WIRE_BYTES);
    float* xp   = (float*)((char*)d_ws + WIRE_BYTES + HFIN_BYTES);

    hipMemsetAsync(wire, 0, WIRE_BYTES, stream);   // tags 0; step0 wants tag 1
    xproj_kernel <<<dim3(2048), dim3(512), 0, stream>>>(x, Wih, bih, bhh, xp);
    rnn_seq8_kernel<<<dim3(256), dim3(512), 0, stream>>>(xp, Whh, wire, hfin);
    rnn_out_kernel<<<dim3(BATCH), dim3(NOUT), 0, stream>>>(hfin, Who, bho, out);
  } else {
    float* hfin = (float*)d_ws;
    float* xp   = (float*)((char*)d_ws + HFIN_BYTES);
    xproj_kernel<<<dim3(2048), dim3(512), 0, stream>>>(x, Wih, bih, bhh, xp);
    rnn_seq_fb_kernel<<<dim3(BATCH), dim3(512), 0, stream>>>(xp, Whh, hfin);
    rnn_out_kernel<<<dim3(BATCH), dim3(NOUT), 0, stream>>>(hfin, Who, bho, out);
  }
}